// Round 13
// baseline (32.315 us; speedup 1.0000x reference)
//
#include <hip/hip_runtime.h>
#include <stdint.h>

#define D_DIM 256
#define K_CTR 1024
#define B_ROWS 16384
#define BM 32

typedef float f32x4 __attribute__((ext_vector_type(4)));
typedef long long i64x2 __attribute__((ext_vector_type(2)));

// Pack 4 f32 -> 4 fp8 e4m3 bytes (OCP, HW cvt).
static __device__ __forceinline__ unsigned cvt4_fp8(const float4 v) {
    int r = __builtin_amdgcn_cvt_pk_fp8_f32(v.x, v.y, 0, false);   // bytes 0-1
    r = __builtin_amdgcn_cvt_pk_fp8_f32(v.z, v.w, r, true);        // bytes 2-3
    return (unsigned)r;
}

// lgkm-only barrier: LDS handoffs need lgkmcnt(0)+s_barrier; global stores
// stay in flight and drain under subsequent compute.
static __device__ __forceinline__ void barrier_lgkm() {
    asm volatile("s_waitcnt lgkmcnt(0)" ::: "memory");
    __builtin_amdgcn_s_barrier();
}

// Prep: centers f32 -> fp8 fragment-major (pair-interleaved) + c_sq f32.
// Value c[col][d] (kk=d>>5, p=kk>>1, e=kk&1, hk=(d>>3)&3, j=d&7) at byte:
//   (col>>4)*4096 + p*1024 + (hk*16 + (col&15))*16 + e*8 + j
// -> main's wave load (lane l) at p*1024 + l*16 is one 1KB dwordx4 holding
//    frags kk=2p (bytes 0-7) and kk=2p+1 (bytes 8-15).
__global__ __launch_bounds__(256) void rbf_prep(const float* __restrict__ centers,
                                                unsigned char* __restrict__ cbf,
                                                float* __restrict__ csq) {
    const int w = threadIdx.x >> 6;
    const int l = threadIdx.x & 63;
    const int c0 = blockIdx.x * 4 + w;
    const float4 v = *reinterpret_cast<const float4*>(centers + c0 * D_DIM + l * 4);
    float s = v.x * v.x + v.y * v.y + v.z * v.z + v.w * v.w;
    const unsigned u = cvt4_fp8(v);
    const unsigned off = (unsigned)((c0 >> 4) * 4096 + (l >> 4) * 1024
                       + (((l >> 1) & 3) * 16 + (c0 & 15)) * 16
                       + ((l >> 3) & 1) * 8 + (l & 1) * 4);
    *reinterpret_cast<unsigned*>(cbf + off) = u;
    #pragma unroll
    for (int off2 = 1; off2 < 64; off2 <<= 1) s += __shfl_xor(s, off2);
    if (l == 0) csq[c0] = s;
}

// Main: 512 thr (8 waves), block = 32 rows (2 strips of 16) x 1024 cols.
// Per strip: 8 BARRIER-FREE subphases (B ping-pong prefetch, 8 MFMA, exp2
// epilogue -> 64KB swizzled obuf covering 16 full output rows), then ONE
// lgkm barrier and a fill-identical ascending store burst: wave w writes
// rows 2w,2w+1 = 8KB contiguous ascending dwordx4 stream. Write-order test.
__global__ __launch_bounds__(512, 4) void rbf_main(const float* __restrict__ x,
                                                   const unsigned char* __restrict__ cbf,
                                                   const float* __restrict__ csq,
                                                   const float* __restrict__ betas,
                                                   float* __restrict__ out) {
    __shared__ __align__(16) unsigned char As[BM * D_DIM];   // 8 KB fp8, swizzled
    __shared__ __align__(16) float obuf[16 * K_CTR];         // 64 KB: 16 full rows
    __shared__ float xs_lds[BM];

    const int tid = threadIdx.x;
    const int w = tid >> 6;
    const int l = tid & 63;
    // XCD-chunked bijective swizzle (512 = 8*64)
    const int strip = (blockIdx.x & 7) * 64 + (blockIdx.x >> 3);
    const int row0 = strip * BM;

    // ---- Stage A strip as fp8 (swizzled) + x_sq ----
    #pragma unroll
    for (int i = 0; i < 4; ++i) {
        const int r = i * 8 + w;
        const float4 v = *reinterpret_cast<const float4*>(x + (size_t)(row0 + r) * D_DIM + l * 4);
        float s = v.x * v.x + v.y * v.y + v.z * v.z + v.w * v.w;
        const unsigned u = cvt4_fp8(v);
        const unsigned pos = (unsigned)((l >> 4) * 64 + ((l >> 1) & 3) * 16
                           + ((l >> 3) & 1) * 8 + (l & 1) * 4);
        *reinterpret_cast<unsigned*>(As + r * 256 + (pos ^ ((unsigned)(r & 7) << 4))) = u;
        #pragma unroll
        for (int off = 1; off < 64; off <<= 1) s += __shfl_xor(s, off);
        if (l == 0) xs_lds[r] = s;
    }

    const int hk = l >> 4;
    const int lr = l & 15;
    const unsigned char* bwave = cbf + l * 16;

    // ---- Issue B(subphase 0) before the barrier ----
    i64x2 b0[4], b1[4];
    {
        const unsigned char* bbase = bwave + w * 4096;
        #pragma unroll
        for (int p = 0; p < 4; ++p)
            b0[p] = *reinterpret_cast<const i64x2*>(bbase + p * 1024);
    }
    barrier_lgkm();   // As + xs_lds handoff

    // ---- Hoist A frags for BOTH strips: 8 ds_read_b128, 32 VGPR ----
    i64x2 a[2][4];
    #pragma unroll
    for (int s = 0; s < 2; ++s) {
        const int r = s * 16 + lr;
        #pragma unroll
        for (int p = 0; p < 4; ++p)
            a[s][p] = *reinterpret_cast<const i64x2*>(
                As + r * 256 + ((unsigned)(p * 64 + hk * 16) ^ ((unsigned)(lr & 7) << 4)));
    }
    const float xsA[2] = { xs_lds[lr], xs_lds[16 + lr] };
    const float LOG2E = 1.4426950408889634f;

    #pragma unroll
    for (int s = 0; s < 2; ++s) {
        // ---- 8 barrier-free subphases; wave w covers colgrp ph*8+w (16 cols) ----
        #pragma unroll
        for (int ph = 0; ph < 8; ++ph) {
            const int t = s * 8 + ph;
            const i64x2 (&bc)[4] = (t & 1) ? b1 : b0;
            i64x2 (&bn)[4] = (t & 1) ? b0 : b1;

            // Prefetch next subphase's B (strip 1 re-reads the same colgrps)
            if (t < 15) {
                const unsigned char* bbase = bwave + (((t + 1) & 7) * 8 + w) * 4096;
                #pragma unroll
                for (int p = 0; p < 4; ++p)
                    bn[p] = *reinterpret_cast<const i64x2*>(bbase + p * 1024);
            }

            // 8 MFMAs into one acc: lane = x-row lr, cols hk*4..+3 of colgrp
            f32x4 acc = {};
            #pragma unroll
            for (int p = 0; p < 4; ++p) {
                acc = __builtin_amdgcn_mfma_f32_16x16x32_fp8_fp8(bc[p][0], a[s][p][0], acc, 0, 0, 0);
                acc = __builtin_amdgcn_mfma_f32_16x16x32_fp8_fp8(bc[p][1], a[s][p][1], acc, 0, 0, 0);
            }

            // Epilogue: exp2(2*bt*log2e*acc - bt*log2e*(xs+cs)) -> swizzled obuf
            const int cl = ph * 128 + w * 16 + hk * 4;    // col 0..1023
            const f32x4 cs = *reinterpret_cast<const f32x4*>(csq + cl);
            const f32x4 bt = *reinterpret_cast<const f32x4*>(betas + cl);
            f32x4 rv;
            #pragma unroll
            for (int j = 0; j < 4; ++j) {
                const float btl2 = bt[j] * LOG2E;
                const float c0 = -btl2 * (xsA[s] + cs[j]);
                rv[j] = __builtin_exp2f(__builtin_fmaf(btl2 + btl2, acc[j], c0));
            }
            *reinterpret_cast<f32x4*>(reinterpret_cast<char*>(obuf)
                + lr * 4096 + ((unsigned)(cl * 4) ^ ((unsigned)(lr & 7) << 4))) = rv;
        }
        barrier_lgkm();   // obuf complete (LDS-only handoff)

        // ---- Fill-identical store burst: wave w -> rows 2w,2w+1 (8KB ascending) ----
        #pragma unroll
        for (int j = 0; j < 2; ++j) {
            const int r = w * 2 + j;
            const unsigned sw = (unsigned)(r & 7) << 4;
            f32x4 sv[4];
            #pragma unroll
            for (int c = 0; c < 4; ++c)
                sv[c] = *reinterpret_cast<const f32x4*>(reinterpret_cast<const char*>(obuf)
                        + r * 4096 + ((unsigned)(l * 16 + c * 1024) ^ sw));
            float* orow = out + (size_t)(row0 + s * 16 + r) * K_CTR;
            #pragma unroll
            for (int c = 0; c < 4; ++c)
                *reinterpret_cast<f32x4*>(orow + c * 256 + l * 4) = sv[c];
        }
        if (s == 0) barrier_lgkm();   // obuf reads retired; safe to rewrite
    }
}

extern "C" void kernel_launch(void* const* d_in, const int* in_sizes, int n_in,
                              void* d_out, int out_size, void* d_ws, size_t ws_size,
                              hipStream_t stream) {
    const float* x       = (const float*)d_in[0];
    const float* centers = (const float*)d_in[1];
    const float* betas   = (const float*)d_in[2];
    float* out = (float*)d_out;

    unsigned char* cbf = (unsigned char*)d_ws;                        // 256 KB fp8 fragment-major centers
    float* csq = (float*)((char*)d_ws + (size_t)K_CTR * D_DIM);       // 4 KB c_sq

    rbf_prep<<<K_CTR / 4, 256, 0, stream>>>(centers, cbf, csq);
    rbf_main<<<B_ROWS / BM, 512, 0, stream>>>(x, cbf, csq, betas, out);
}

// Round 14
// 31.687 us; speedup vs baseline: 1.0198x; 1.0198x over previous
//
#include <hip/hip_runtime.h>
#include <stdint.h>

#define D_DIM 256
#define K_CTR 1024
#define B_ROWS 16384
#define BM 32

typedef float f32x4 __attribute__((ext_vector_type(4)));
typedef float f32x2 __attribute__((ext_vector_type(2)));
typedef long long i64x2 __attribute__((ext_vector_type(2)));

// Pack 4 f32 -> 4 fp8 e4m3 bytes (OCP, HW cvt).
static __device__ __forceinline__ unsigned cvt4_fp8(const float4 v) {
    int r = __builtin_amdgcn_cvt_pk_fp8_f32(v.x, v.y, 0, false);   // bytes 0-1
    r = __builtin_amdgcn_cvt_pk_fp8_f32(v.z, v.w, r, true);        // bytes 2-3
    return (unsigned)r;
}

// lgkm-only barrier for the single LDS handoff (A-stage). Global ops uncounted.
static __device__ __forceinline__ void barrier_lgkm() {
    asm volatile("s_waitcnt lgkmcnt(0)" ::: "memory");
    __builtin_amdgcn_s_barrier();
}

// Prep: centers f32 -> fp8 fragment-major (pair-interleaved) + c_sq f32.
// Value c[col][d] (kk=d>>5, p=kk>>1, e=kk&1, hk=(d>>3)&3, j=d&7) at byte:
//   (col>>4)*4096 + p*1024 + (hk*16 + (col&15))*16 + e*8 + j
// -> main's wave load (lane l) at p*1024 + l*16 is one 1KB dwordx4 holding
//    frags kk=2p (bytes 0-7) and kk=2p+1 (bytes 8-15).
__global__ __launch_bounds__(256) void rbf_prep(const float* __restrict__ centers,
                                                unsigned char* __restrict__ cbf,
                                                float* __restrict__ csq) {
    const int w = threadIdx.x >> 6;
    const int l = threadIdx.x & 63;
    const int c0 = blockIdx.x * 4 + w;
    const float4 v = *reinterpret_cast<const float4*>(centers + c0 * D_DIM + l * 4);
    float s = v.x * v.x + v.y * v.y + v.z * v.z + v.w * v.w;
    const unsigned u = cvt4_fp8(v);
    const unsigned off = (unsigned)((c0 >> 4) * 4096 + (l >> 4) * 1024
                       + (((l >> 1) & 3) * 16 + (c0 & 15)) * 16
                       + ((l >> 3) & 1) * 8 + (l & 1) * 4);
    *reinterpret_cast<unsigned*>(cbf + off) = u;
    #pragma unroll
    for (int off2 = 1; off2 < 64; off2 <<= 1) s += __shfl_xor(s, off2);
    if (l == 0) csq[c0] = s;
}

// Main: 512 thr (8 waves), block = 32 rows x 1024 cols. ZERO barriers after the
// A-stage handoff: wave w owns 16 rows (s=w>>2) x 256 cols (q=w&3) with a
// PRIVATE 8KB obuf slice. Per wave: 16 colgroup iters {B ping-pong prefetch,
// 8 MFMA (setprio), exp2 epilogue, swizzled ds_write}; after every 8 cgs a
// private store burst (16 rows x 512B single-segment dwordx2). Waves drift ->
// at any instant different waves occupy different pipes (TCP/MFMA/TRANS/DS/store).
__global__ __launch_bounds__(512, 4) void rbf_main(const float* __restrict__ x,
                                                   const unsigned char* __restrict__ cbf,
                                                   const float* __restrict__ csq,
                                                   const float* __restrict__ betas,
                                                   float* __restrict__ out) {
    __shared__ __align__(16) unsigned char As[BM * D_DIM];   // 8 KB fp8, swizzled
    __shared__ __align__(16) float obuf[8][16 * 128];        // 8 x 8 KB wave-private
    __shared__ float xs_lds[BM];

    const int tid = threadIdx.x;
    const int w = tid >> 6;
    const int l = tid & 63;
    // XCD-chunked bijective swizzle (512 = 8*64)
    const int strip = (blockIdx.x & 7) * 64 + (blockIdx.x >> 3);
    const int row0 = strip * BM;

    // ---- Stage A strip as fp8 (swizzled) + x_sq ----
    #pragma unroll
    for (int i = 0; i < 4; ++i) {
        const int r = i * 8 + w;
        const float4 v = *reinterpret_cast<const float4*>(x + (size_t)(row0 + r) * D_DIM + l * 4);
        float s = v.x * v.x + v.y * v.y + v.z * v.z + v.w * v.w;
        const unsigned u = cvt4_fp8(v);
        const unsigned pos = (unsigned)((l >> 4) * 64 + ((l >> 1) & 3) * 16
                           + ((l >> 3) & 1) * 8 + (l & 1) * 4);
        *reinterpret_cast<unsigned*>(As + r * 256 + (pos ^ ((unsigned)(r & 7) << 4))) = u;
        #pragma unroll
        for (int off = 1; off < 64; off <<= 1) s += __shfl_xor(s, off);
        if (l == 0) xs_lds[r] = s;
    }

    const int hk = l >> 4;
    const int lr = l & 15;
    const int s = w >> 2;          // strip half: rows s*16..s*16+15
    const int q = w & 3;           // col quarter: cols q*256..q*256+255
    const unsigned char* bwave = cbf + l * 16;

    // ---- Issue B(cg 0) before the barrier ----
    i64x2 b0[4], b1[4];
    {
        const unsigned char* bbase = bwave + (q * 16) * 4096;
        #pragma unroll
        for (int p = 0; p < 4; ++p)
            b0[p] = *reinterpret_cast<const i64x2*>(bbase + p * 1024);
    }
    barrier_lgkm();   // the ONLY barrier: As + xs_lds handoff

    // ---- Hoist this wave's A frags (strip s): 4 ds_read_b128 ----
    i64x2 a[4];
    #pragma unroll
    for (int p = 0; p < 4; ++p)
        a[p] = *reinterpret_cast<const i64x2*>(
            As + (s * 16 + lr) * 256 + ((unsigned)(p * 64 + hk * 16) ^ ((unsigned)(lr & 7) << 4)));
    const float xs = xs_lds[s * 16 + lr];
    const float LOG2E = 1.4426950408889634f;

    char* ob = reinterpret_cast<char*>(obuf[w]);                       // private 8 KB
    float* orow0 = out + (size_t)(row0 + s * 16) * K_CTR + q * 256;    // wave's out base

    #pragma unroll
    for (int cg = 0; cg < 16; ++cg) {
        const int colgrp = q * 16 + cg;
        const i64x2 (&bc)[4] = (cg & 1) ? b1 : b0;
        i64x2 (&bn)[4] = (cg & 1) ? b0 : b1;

        // ---- Prefetch B(cg+1) ----
        if (cg < 15) {
            const unsigned char* bbase = bwave + (colgrp + 1) * 4096;
            #pragma unroll
            for (int p = 0; p < 4; ++p)
                bn[p] = *reinterpret_cast<const i64x2*>(bbase + p * 1024);
        }

        // ---- 8 MFMAs -> acc (lane: row lr of strip, cols colgrp*16+hk*4..+3) ----
        f32x4 acc = {};
        __builtin_amdgcn_s_setprio(1);
        #pragma unroll
        for (int p = 0; p < 4; ++p) {
            acc = __builtin_amdgcn_mfma_f32_16x16x32_fp8_fp8(bc[p][0], a[p][0], acc, 0, 0, 0);
            acc = __builtin_amdgcn_mfma_f32_16x16x32_fp8_fp8(bc[p][1], a[p][1], acc, 0, 0, 0);
        }
        __builtin_amdgcn_s_setprio(0);

        // ---- Epilogue: exp2(fma(2*bt*log2e, acc, -bt*log2e*(xs+cs))) ----
        const int c0g = colgrp * 16 + hk * 4;
        const f32x4 cs = *reinterpret_cast<const f32x4*>(csq + c0g);
        const f32x4 bt = *reinterpret_cast<const f32x4*>(betas + c0g);
        f32x4 rv;
        #pragma unroll
        for (int j = 0; j < 4; ++j) {
            const float btl2 = bt[j] * LOG2E;
            const float cc = -btl2 * (xs + cs[j]);
            rv[j] = __builtin_exp2f(__builtin_fmaf(btl2 + btl2, acc[j], cc));
        }
        // Swizzled private obuf write: row lr, local col (cg&7)*16 + hk*4
        *reinterpret_cast<f32x4*>(ob + lr * 512
            + ((unsigned)((cg & 7) * 64 + hk * 16) ^ ((unsigned)(lr & 7) << 4))) = rv;

        // ---- Every 8 cgs: private store burst, 16 rows x 512B single-segment ----
        if ((cg & 7) == 7) {
            const int bst = cg >> 3;
            #pragma unroll
            for (int r = 0; r < 16; ++r) {
                const f32x2 v = *reinterpret_cast<const f32x2*>(ob + r * 512
                        + ((unsigned)(l * 8) ^ ((unsigned)(r & 7) << 4)));
                *reinterpret_cast<f32x2*>(orow0 + (size_t)r * K_CTR + bst * 128 + l * 2) = v;
            }
        }
    }
}

extern "C" void kernel_launch(void* const* d_in, const int* in_sizes, int n_in,
                              void* d_out, int out_size, void* d_ws, size_t ws_size,
                              hipStream_t stream) {
    const float* x       = (const float*)d_in[0];
    const float* centers = (const float*)d_in[1];
    const float* betas   = (const float*)d_in[2];
    float* out = (float*)d_out;

    unsigned char* cbf = (unsigned char*)d_ws;                        // 256 KB fp8 fragment-major centers
    float* csq = (float*)((char*)d_ws + (size_t)K_CTR * D_DIM);       // 4 KB c_sq

    rbf_prep<<<K_CTR / 4, 256, 0, stream>>>(centers, cbf, csq);
    rbf_main<<<B_ROWS / BM, 512, 0, stream>>>(x, cbf, csq, betas, out);
}